// Round 5
// baseline (372.206 us; speedup 1.0000x reference)
//
#include <hip/hip_runtime.h>

// VectorQuantizer on MI355X — R5 (= R4 with the femb stride bug fixed).
// R4 bug: pack wrote 8KB/tile (kc only 0..3, k<128 packed) while vq_main DMA'd 16KB/tile
// at 8KB stride -> scrambled codebook. R5: pack 16KB/tile (kc 0..7), DMA stride 16384.
// Structure: MB=64/256thr/NT=32, LDS ~70KB -> 2 blocks/CU (grid 512) so co-resident
// blocks cover each other's barrier+DMA drains; static Bs0/Bs1 double-buffer.

#define D        256
#define KCODES   8192
#define NROWS    32768
#define MB       64       // rows per block
#define NT       32       // codes per tile
#define NTILES   (KCODES / NT)   // 256
#define THREADS  256
#define CAP      32
#define MARGIN   0.03f
#define BIAS     32.0f
#define NOUT     8388608

typedef _Float16 h8_t __attribute__((ext_vector_type(8)));
typedef float    f4_t __attribute__((ext_vector_type(4)));

__device__ __forceinline__ float clipf(float v) { return fminf(1.0f, fmaxf(-1.0f, v)); }

#define DPP_ROR(x, n) __int_as_float(__builtin_amdgcn_update_dpp( \
    0, __float_as_int(x), 0x120 + (n), 0xF, 0xF, true))
__device__ __forceinline__ float maxrow16(float x) {
  x = fmaxf(x, DPP_ROR(x, 1));
  x = fmaxf(x, DPP_ROR(x, 2));
  x = fmaxf(x, DPP_ROR(x, 4));
  x = fmaxf(x, DPP_ROR(x, 8));
  return x;
}

__device__ __forceinline__ void gld_lds16(const void* g, void* l) {
  __builtin_amdgcn_global_load_lds(
      (const __attribute__((address_space(1))) unsigned int*)g,
      (__attribute__((address_space(3))) unsigned int*)l, 16, 0, 0);
}

// ---- pack f16 codebook (fragment-major, DMA-linear, 16KB per 32-code tile) + sums ----
// chunk c in [0,1024): kc=c>>7 (0..7), ng=(c>>6)&1, ln=c&63;
// content = emb16[t*32 + ng*16 + (ln&15)][kc*32 + (ln>>4)*8 .. +8]
__global__ void vq_packsetup(const float* __restrict__ emb, _Float16* __restrict__ femb,
                             float* __restrict__ senp, float* __restrict__ ekkb,
                             float* __restrict__ lossacc) {
  const int t = blockIdx.x;
  if (t == 0 && threadIdx.x == 0) lossacc[0] = 0.0f;
  #pragma unroll
  for (int j = 0; j < 4; ++j) {
    int c = j * 256 + threadIdx.x;        // 0..1023
    int kc = c >> 7, ng = (c >> 6) & 1, ln = c & 63;
    int code = t * 32 + ng * 16 + (ln & 15);
    int k0 = kc * 32 + (ln >> 4) * 8;
    const float* sp = emb + (size_t)code * D + k0;
    f4_t v0 = *(const f4_t*)sp, v1 = *(const f4_t*)(sp + 4);
    h8_t h;
    h[0] = (_Float16)v0[0]; h[1] = (_Float16)v0[1];
    h[2] = (_Float16)v0[2]; h[3] = (_Float16)v0[3];
    h[4] = (_Float16)v1[0]; h[5] = (_Float16)v1[1];
    h[6] = (_Float16)v1[2]; h[7] = (_Float16)v1[3];
    *(h8_t*)(femb + (size_t)t * 8192 + (size_t)c * 8) = h;   // 16KB/tile (halves)
  }
  // numpy-pairwise-order sum(e^2); butterfly == same binary tree (commutative reorder only)
  const int lane = threadIdx.x & 63;
  const int w    = threadIdx.x >> 6;
  const int jdx  = lane & 15, hf = jdx >> 3, jj = jdx & 7;
  #pragma unroll
  for (int cc = 0; cc < 2; ++cc) {
    int k = t * 32 + w * 8 + cc * 4 + (lane >> 4);
    const float* base = emb + (size_t)k * D + hf * 128 + jj;
    float v = base[0];
    float r = v * v;
    #pragma unroll
    for (int m = 1; m < 16; ++m) { v = base[8 * m]; r += v * v; }
    r += __shfl_xor(r, 1, 64);
    r += __shfl_xor(r, 2, 64);
    r += __shfl_xor(r, 4, 64);
    r += __shfl_xor(r, 8, 64);
    if (jdx == 0) { senp[k] = r; ekkb[k] = 0.5f * r - BIAS; }
  }
}

// ---------------- main ----------------
__global__ void __launch_bounds__(THREADS, 2)
vq_main(const float* __restrict__ xin, const _Float16* __restrict__ femb,
        const float* __restrict__ emb, const float* __restrict__ senp,
        const float* __restrict__ ekkb, float* __restrict__ out,
        float* __restrict__ lossacc) {
  __shared__ alignas(16) char Bs0[16384];
  __shared__ alignas(16) char Bs1[16384];
  __shared__ float Eks[KCODES];              // 32 KB
  __shared__ int rowmaxI[MB];
  __shared__ int cnt[MB];
  __shared__ unsigned short cand[MB][CAP];   // 4 KB
  __shared__ float blksum;                   // total ~70 KB -> 2 blocks/CU

  const int tid  = threadIdx.x;
  const int lane = tid & 63;
  const int wid  = tid >> 6;     // 0..3
  const int l15  = lane & 15;
  const int quad = lane >> 4;
  const int rw   = wid >> 1;     // 0..1 : 32-row group
  const int ng   = wid & 1;      // 0..1 : 16-col group
  const int ng16 = ng * 16;
  const int r0   = blockIdx.x * MB;

  for (int i = tid; i < MB; i += THREADS) { rowmaxI[i] = 0; cnt[i] = 0; }
  if (tid == 0) blksum = 0.0f;

  // ---- stage ekk table into LDS (lgkm-only thereafter)
  #pragma unroll
  for (int i = 0; i < 8; ++i) {
    int e = (i * THREADS + tid) * 4;
    *(f4_t*)&Eks[e] = *(const f4_t*)&ekkb[e];
  }

  // ---- stage x-tile (clipped f16, fragment order): 2048 chunks over Bs0|Bs1
  #pragma unroll
  for (int j = 0; j < 8; ++j) {
    int c = j * THREADS + tid;            // 0..2047
    int kc = c >> 8, g = (c >> 6) & 3, ln = c & 63;
    int row = g * 16 + (ln & 15);
    int k0 = kc * 32 + (ln >> 4) * 8;
    const float* ap = xin + (size_t)(r0 + row) * D + k0;
    f4_t v0 = *(const f4_t*)ap, v1 = *(const f4_t*)(ap + 4);
    h8_t h;
    h[0] = (_Float16)clipf(v0[0]); h[1] = (_Float16)clipf(v0[1]);
    h[2] = (_Float16)clipf(v0[2]); h[3] = (_Float16)clipf(v0[3]);
    h[4] = (_Float16)clipf(v1[0]); h[5] = (_Float16)clipf(v1[1]);
    h[6] = (_Float16)clipf(v1[2]); h[7] = (_Float16)clipf(v1[3]);
    char* dst = (c < 1024) ? (Bs0 + c * 16) : (Bs1 + c * 16 - 16384);
    *(h8_t*)dst = h;
  }
  __syncthreads();

  // ---- A fragments -> registers: rows rw*32 + ms*16 + l15
  h8_t afrag0[8], afrag1[8];
  #pragma unroll
  for (int kc = 0; kc < 8; ++kc) {
    {
      int c = kc * 256 + (rw * 2 + 0) * 64 + lane;
      afrag0[kc] = (kc < 4) ? *(const h8_t*)(Bs0 + c * 16)
                            : *(const h8_t*)(Bs1 + c * 16 - 16384);
    }
    {
      int c = kc * 256 + (rw * 2 + 1) * 64 + lane;
      afrag1[kc] = (kc < 4) ? *(const h8_t*)(Bs0 + c * 16)
                            : *(const h8_t*)(Bs1 + c * 16 - 16384);
    }
  }
  __syncthreads();   // reads done before DMA overwrites buffers

  const char* gth = (const char*)femb + (size_t)(wid * 4096 + lane * 16);

#define PREFETCH(tt, BUF) do {                              \
    const char* g2_ = gth + (size_t)(tt) * 16384;           \
    gld_lds16(g2_,        BUF + wid * 4096);                \
    gld_lds16(g2_ + 1024, BUF + wid * 4096 + 1024);         \
    gld_lds16(g2_ + 2048, BUF + wid * 4096 + 2048);         \
    gld_lds16(g2_ + 3072, BUF + wid * 4096 + 3072);         \
  } while (0)

  float Lbm0[4], Lbm1[4];
  #pragma unroll
  for (int b = 0; b < 4; ++b) { Lbm0[b] = -1e30f; Lbm1[b] = -1e30f; }

#define FILTER(ACC, MS, LBM, C0) do {                                         \
    _Pragma("unroll")                                                         \
    for (int r = 0; r < 4; ++r) {                                             \
      float t0 = (ACC)[r] - ekk;                                              \
      if (__any(t0 > LBM[r])) {                                               \
        int row_ = rw * 32 + (MS) * 16 + quad * 4 + r;                        \
        float mm_ = maxrow16(t0);                                             \
        if (l15 == 0) atomicMax(&rowmaxI[row_], __float_as_int(mm_));         \
        float cut_ = __int_as_float(rowmaxI[row_]) - MARGIN;                  \
        LBM[r] = cut_;                                                        \
        if (t0 >= cut_) {                                                     \
          int s_ = atomicAdd(&cnt[row_], 1);                                  \
          if (s_ < CAP) cand[row_][s_] = (unsigned short)((C0) + ng16 + l15); \
        }                                                                     \
      }                                                                       \
    }                                                                         \
  } while (0)

#define COMPUTE(tt, BUF) do {                                                 \
    const int c0_ = (tt) * NT;                                                \
    float ekk = Eks[c0_ + ng16 + l15];                                        \
    f4_t a0 = {0.f, 0.f, 0.f, 0.f}, a1 = {0.f, 0.f, 0.f, 0.f};                \
    _Pragma("unroll")                                                         \
    for (int kc = 0; kc < 8; ++kc) {                                          \
      h8_t b = *(const h8_t*)(BUF + (kc * 2 + ng) * 1024 + lane * 16);        \
      a0 = __builtin_amdgcn_mfma_f32_16x16x32_f16(afrag0[kc], b, a0, 0, 0, 0);\
      a1 = __builtin_amdgcn_mfma_f32_16x16x32_f16(afrag1[kc], b, a1, 0, 0, 0);\
    }                                                                         \
    FILTER(a0, 0, Lbm0, c0_);                                                 \
    FILTER(a1, 1, Lbm1, c0_);                                                 \
  } while (0)

  PREFETCH(0, Bs0);
  for (int t = 0; t < NTILES; t += 2) {
    __syncthreads();                 // DMA(t)->Bs0 drained; Bs1 reads done
    PREFETCH(t + 1, Bs1);
    COMPUTE(t, Bs0);
    __syncthreads();                 // DMA(t+1)->Bs1 drained; Bs0 reads done
    if (t + 2 < NTILES) PREFETCH(t + 2, Bs0);
    COMPUTE(t + 1, Bs1);
  }
  __syncthreads();

  // ---------------- exact rescore + output + loss (scratch over Bs0) ----------------
  float* xrow  = (float*)Bs0;           // 4 waves x 256 floats
  float* rpart = (float*)(Bs0 + 4096);  // 4 waves x 16 floats
  const int lane4 = lane * 4;
  for (int rr = 0; rr < 16; ++rr) {
    const int row = wid + rr * 4;
    f4_t xv = *(const f4_t*)(xin + (size_t)(r0 + row) * D + lane4);
    xv[0] = clipf(xv[0]); xv[1] = clipf(xv[1]); xv[2] = clipf(xv[2]); xv[3] = clipf(xv[3]);
    *(f4_t*)&xrow[wid * 256 + lane4] = xv;
    __builtin_amdgcn_wave_barrier();
    if (lane < 16) {   // numpy pairwise sum of x^2 (exact order)
      const int hf = lane >> 3, jj = lane & 7;
      const float* base = &xrow[wid * 256 + hf * 128 + jj];
      float v = base[0];
      float rs = v * v;
      #pragma unroll
      for (int m = 1; m < 16; ++m) { v = base[8 * m]; rs += v * v; }
      rpart[wid * 16 + lane] = rs;
    }
    __builtin_amdgcn_wave_barrier();
    float p[16];
    #pragma unroll
    for (int j = 0; j < 16; ++j) p[j] = rpart[wid * 16 + j];
    float h0 = ((p[0] + p[1]) + (p[2] + p[3])) + ((p[4] + p[5]) + (p[6] + p[7]));
    float h1 = ((p[8] + p[9]) + (p[10] + p[11])) + ((p[12] + p[13]) + (p[14] + p[15]));
    float sx = h0 + h1;

    int nc = cnt[row]; nc = nc > CAP ? CAP : nc;
    float bd = INFINITY; int bk = 0;
    for (int ci = 0; ci < nc; ++ci) {
      int k = cand[row][ci];
      f4_t ev = *(const f4_t*)(emb + (size_t)k * D + lane4);
      double dd = (double)xv[0] * (double)ev[0] + (double)xv[1] * (double)ev[1]
                + (double)xv[2] * (double)ev[2] + (double)xv[3] * (double)ev[3];
      #pragma unroll
      for (int off = 1; off < 64; off <<= 1) dd += __shfl_xor(dd, off, 64);
      float T1 = sx + senp[k];          // fp32, numpy op order
      float T2 = (float)(2.0 * dd);     // fp32-rounded 2*dot
      float d  = T1 - T2;               // final fp32 quantization like numpy
      if (d < bd || (d == bd && k < bk)) { bd = d; bk = k; }
    }

    f4_t ev = *(const f4_t*)(emb + (size_t)bk * D + lane4);
    *(f4_t*)(out + (size_t)(r0 + row) * D + lane4) = ev;
    float ls = 0.0f;
    #pragma unroll
    for (int i = 0; i < 4; ++i) { float df = ev[i] - xv[i]; ls += df * df; }
    #pragma unroll
    for (int off = 1; off < 64; off <<= 1) ls += __shfl_xor(ls, off, 64);
    if (lane == 0) atomicAdd(&blksum, ls);
  }
  __syncthreads();
  if (tid == 0) atomicAdd(lossacc, blksum);
}

// ---------------- finalize loss ----------------
__global__ void vq_fin(const float* __restrict__ lossacc, float* __restrict__ out) {
  out[NOUT] = 1.25f * lossacc[0] / 8388608.0f;
}

extern "C" void kernel_launch(void* const* d_in, const int* in_sizes, int n_in,
                              void* d_out, int out_size, void* d_ws, size_t ws_size,
                              hipStream_t stream) {
  const float* xin = (const float*)d_in[0];
  const float* emb = (const float*)d_in[1];
  float* out = (float*)d_out;
  _Float16* femb = (_Float16*)d_ws;                 // 4 MB (256 tiles x 16 KB)
  float* wsf     = (float*)d_ws;
  float* senp    = wsf + 1048576;                   // 8192 floats
  float* ekkb    = senp + KCODES;                   // 8192 floats
  float* lossacc = ekkb + KCODES;                   // 1 float
  vq_packsetup<<<dim3(NTILES), dim3(256), 0, stream>>>(emb, femb, senp, ekkb, lossacc);
  vq_main<<<dim3(NROWS / MB), dim3(THREADS), 0, stream>>>(xin, femb, emb, senp, ekkb, out, lossacc);
  vq_fin<<<dim3(1), dim3(1), 0, stream>>>(lossacc, out);
}